// Round 7
// baseline (4538.995 us; speedup 1.0000x reference)
//
#include <hip/hip_runtime.h>

// ---------------------------------------------------------------------------
// Persistent fused 2-layer LSTM + FC for MI355X — v7: decoupled layer domains.
//  - Grid (48,4): per batch-group g (16 batches): 16 L0-WGs + 32 L1-WGs.
//  - L0-WG: 4 waves x 8 units, full-K(576). Self-syncs on h0 ring (D0=5),
//    runs AHEAD of L1 (slack), throttled by L1-progress back-pressure.
//  - L1-WG: 4 waves x 4 units, full-K(1024). Self-syncs on h1 ring (D1=3);
//    reads h0(u) as stale input (L0 ahead => first-try tag hit, no wait).
//  - No cross-layer barrier anywhere: each chain's critical path is its own
//    32KB / <=32-producer domain; cross-layer jitter absorbed by ring slack.
//  - Exchange: u32 = fp16|(tag<<16), agent-scope atomics (v2/v6-proven).
//  - Back-pressure invariant: L0 stores h0(t) only after all L1 published
//    progress >= t-4 (publish happens post-barrier => all verify loads done).
// ---------------------------------------------------------------------------

#define H      512
#define T_SEQ  1024
#define DIN    64

#define D0       5
#define D1       3
#define H0_SLOT  8192            // [16 batch][512 units] tagged u32
#define H1_OFF   40960           // D0 * H0_SLOT
#define PROG_OFF 65536           // H1_OFF + D1 * H0_SLOT
#define GRP_U32  65792           // padded
#define WS_BYTES (4 * GRP_U32 * 4)

typedef _Float16 f16x8 __attribute__((ext_vector_type(8)));
typedef float    f32x4 __attribute__((ext_vector_type(4)));
typedef unsigned long long u64t;

__device__ __forceinline__ u64t ld_u64(const u64t* p) {
  return __hip_atomic_load((u64t*)p, __ATOMIC_RELAXED, __HIP_MEMORY_SCOPE_AGENT);
}
__device__ __forceinline__ unsigned ld_u32a(const unsigned* p) {
  return __hip_atomic_load((unsigned*)p, __ATOMIC_RELAXED, __HIP_MEMORY_SCOPE_AGENT);
}
__device__ __forceinline__ void st_u32(unsigned* p, unsigned v) {
  __hip_atomic_store(p, v, __ATOMIC_RELAXED, __HIP_MEMORY_SCOPE_AGENT);
}
__device__ __forceinline__ f16x8 pk8(float4 a, float4 b) {
  f16x8 r;
  r[0] = (_Float16)a.x; r[1] = (_Float16)a.y; r[2] = (_Float16)a.z; r[3] = (_Float16)a.w;
  r[4] = (_Float16)b.x; r[5] = (_Float16)b.y; r[6] = (_Float16)b.z; r[7] = (_Float16)b.w;
  return r;
}
__device__ __forceinline__ f16x8 cvt8(const float* p) {
  return pk8(*(const float4*)p, *(const float4*)(p + 4));
}
__device__ __forceinline__ f32x4 mfma16(f16x8 a, f16x8 b, f32x4 c) {
  return __builtin_amdgcn_mfma_f32_16x16x32_f16(a, b, c, 0, 0, 0);
}
__device__ __forceinline__ float rcpf_(float x) {
#if __has_builtin(__builtin_amdgcn_rcpf)
  return __builtin_amdgcn_rcpf(x);
#else
  return 1.0f / x;
#endif
}
__device__ __forceinline__ float sigm(float x) {
  x = fminf(fmaxf(x, -30.f), 30.f);
  return rcpf_(1.f + __expf(-x));
}
__device__ __forceinline__ float tanhx(float x) {
  x = fminf(fmaxf(x, -15.f), 15.f);
  float e = __expf(2.f * x);
  return (e - 1.f) * rcpf_(e + 1.f);
}
__device__ __forceinline__ unsigned payload(u64t v) {
  return ((unsigned)v & 0xffffu) | ((unsigned)(v >> 32) << 16);
}

__global__ __launch_bounds__(256, 1)
void lstm_fused(const float* __restrict__ x,
                const float* __restrict__ Wih0, const float* __restrict__ Whh0,
                const float* __restrict__ bih0, const float* __restrict__ bhh0,
                const float* __restrict__ Wih1, const float* __restrict__ Whh1,
                const float* __restrict__ bih1, const float* __restrict__ bhh1,
                const float* __restrict__ fcw,  const float* __restrict__ fcb,
                float* __restrict__ out, unsigned* __restrict__ ws)
{
  // [2 buf][2 region][16 rows][260 u32]; L0 uses region 0 only
  __shared__ unsigned sH[2 * 8320];

  const int tid  = threadIdx.x;
  const int r    = blockIdx.x;          // 0..47 within group
  const int g    = blockIdx.y;          // batch group 0..3
  const int wv   = tid >> 6;
  const int lane = tid & 63;
  const int bcol = lane & 15;
  const int kgrp = lane >> 4;
  const bool isL0 = (r < 16);

  unsigned* gbase = ws + g * GRP_U32;
  unsigned* prog  = gbase + PROG_OFF;   // 32 words, one per L1-WG

  const int src_m = lane & 15;
  const int hb = isL0 ? (r * 32 + wv * 8) : ((r - 16) * 16 + wv * 4);
  const int gr0 = (src_m & 3) * H + hb + (src_m >> 2);   // PyTorch gate row

  // ---- resident weights
  f16x8 wA[36];
  if (isL0) {
    const int gr1 = gr0 + 4;
    #pragma unroll
    for (int f = 0; f < 18; ++f) {      // K = 64(x) + 512(h0)
      const float *p0, *p1;
      if (f < 2) {
        p0 = Wih0 + (size_t)gr0 * DIN + f * 32 + kgrp * 8;
        p1 = Wih0 + (size_t)gr1 * DIN + f * 32 + kgrp * 8;
      } else {
        p0 = Whh0 + (size_t)gr0 * H + (f - 2) * 32 + kgrp * 8;
        p1 = Whh0 + (size_t)gr1 * H + (f - 2) * 32 + kgrp * 8;
      }
      wA[f] = cvt8(p0); wA[18 + f] = cvt8(p1);
    }
  } else {
    #pragma unroll
    for (int f = 0; f < 16; ++f)        // K = 512(h0) + 512(h1)
      wA[f] = cvt8(Wih1 + (size_t)gr0 * H + f * 32 + kgrp * 8);
    #pragma unroll
    for (int f = 0; f < 16; ++f)
      wA[16 + f] = cvt8(Whh1 + (size_t)gr0 * H + f * 32 + kgrp * 8);
  }
  float bias0[4], bias1[4];
  {
    const float* bi = isL0 ? bih0 : bih1;
    const float* bh = isL0 ? bhh0 : bhh1;
    #pragma unroll
    for (int rr = 0; rr < 4; ++rr) {
      int u0 = hb + kgrp;
      bias0[rr] = bi[rr * H + u0] + bh[rr * H + u0];
      int u1 = hb + 4 + kgrp;           // only meaningful for L0 tile 1
      bias1[rr] = isL0 ? (bi[rr * H + u1] + bh[rr * H + u1]) : 0.f;
    }
  }

  for (int i = tid; i < 2 * 8320; i += 256) sH[i] = 0;
  __syncthreads();

  unsigned spins = 0;
  const int rowb = bcol * 1040 + kgrp * 16;

  if (isL0) {
    // =================== layer-0 chain (self-sync on h0) ===================
    float c0 = 0.f, c1 = 0.f;
    for (int t = 0; t < T_SEQ; ++t) {
      const float* xp = x + ((size_t)((g * 16 + bcol) * T_SEQ + t)) * DIN + kgrp * 8;
      float4 xr0 = *(const float4*)xp;        float4 xr1 = *(const float4*)(xp + 4);
      float4 xr2 = *(const float4*)(xp + 32); float4 xr3 = *(const float4*)(xp + 36);
      if (t > 0) {
        const u64t* src = (const u64t*)(gbase + ((t - 1) % D0) * H0_SLOT);
        const unsigned want = (unsigned)t;
        u64t v[16];
        #pragma unroll
        for (int i = 0; i < 16; ++i) v[i] = ld_u64(src + tid + i * 256);
        for (;;) {
          unsigned bad = 0;
          #pragma unroll
          for (int i = 0; i < 16; ++i) {
            unsigned lo = (unsigned)v[i], hi = (unsigned)(v[i] >> 32);
            if (((lo >> 16) ^ want) | ((hi >> 16) ^ want)) bad |= (1u << i);
          }
          if (!bad) break;
          if (++spins > 4000000u) break;
          #pragma unroll
          for (int i = 0; i < 16; ++i)
            if (bad & (1u << i)) v[i] = ld_u64(src + tid + i * 256);
        }
        // back-pressure: all L1 staged h0(t-5)  (wave0 spins, others at barrier)
        if (wv == 0) {
          int pv = (lane < 32) ? (int)ld_u32a(prog + lane) : 0x7fffffff;
          while (!__all(pv >= t - 4)) {
            if (++spins > 4000000u) break;
            if (lane < 32) pv = (int)ld_u32a(prog + lane);
          }
        }
        unsigned* db = sH + (t & 1) * 8320;
        #pragma unroll
        for (int i = 0; i < 16; ++i) {
          int j = tid + i * 256;                 // [16][256] u64 index
          db[(j >> 8) * 260 + (j & 255)] = payload(v[i]);
        }
      }
      __syncthreads();

      const char* cur = (const char*)(sH + (t & 1) * 8320);
      f32x4 a0 = {0,0,0,0}, a1 = {0,0,0,0};
      {
        f16x8 b0 = pk8(xr0, xr1);
        a0 = mfma16(wA[0], b0, a0); a1 = mfma16(wA[18], b0, a1);
        f16x8 b1 = pk8(xr2, xr3);
        a0 = mfma16(wA[1], b1, a0); a1 = mfma16(wA[19], b1, a1);
      }
      #pragma unroll
      for (int f = 2; f < 18; ++f) {
        f16x8 bf = *(const f16x8*)(cur + rowb + (f - 2) * 64);
        a0 = mfma16(wA[f], bf, a0); a1 = mfma16(wA[18 + f], bf, a1);
      }
      float hv0, hv1;
      {
        float ii = sigm(a0[0] + bias0[0]);
        float ff = sigm(a0[1] + bias0[1]);
        float gg = tanhx(a0[2] + bias0[2]);
        float oo = sigm(a0[3] + bias0[3]);
        c0 = ff * c0 + ii * gg;  hv0 = oo * tanhx(c0);
      }
      {
        float ii = sigm(a1[0] + bias1[0]);
        float ff = sigm(a1[1] + bias1[1]);
        float gg = tanhx(a1[2] + bias1[2]);
        float oo = sigm(a1[3] + bias1[3]);
        c1 = ff * c1 + ii * gg;  hv1 = oo * tanhx(c1);
      }
      unsigned tag = (unsigned)(t + 1) << 16;
      unsigned u0 = (unsigned)__builtin_bit_cast(unsigned short, (_Float16)hv0);
      unsigned u1 = (unsigned)__builtin_bit_cast(unsigned short, (_Float16)hv1);
      unsigned* dst = gbase + (t % D0) * H0_SLOT + bcol * 512 + hb + kgrp;
      st_u32(dst,     u0 | tag);
      st_u32(dst + 4, u1 | tag);
    }
  } else {
    // =================== layer-1 chain (self-sync on h1) ===================
    const int q = r - 16;
    float c0 = 0.f;
    for (int u = 0; u < T_SEQ; ++u) {
      const u64t* s0 = (const u64t*)(gbase + (u % D0) * H0_SLOT);
      const u64t* s1 = (const u64t*)(gbase + H1_OFF + ((u + 2) % D1) * H0_SLOT);
      const unsigned w0 = (unsigned)(u + 1), w1 = (unsigned)u;
      u64t v0[16], v1[16];
      #pragma unroll
      for (int i = 0; i < 16; ++i) v0[i] = ld_u64(s0 + tid + i * 256);
      if (u > 0) {
        #pragma unroll
        for (int i = 0; i < 16; ++i) v1[i] = ld_u64(s1 + tid + i * 256);
      }
      for (;;) {
        unsigned bad0 = 0, bad1 = 0;
        #pragma unroll
        for (int i = 0; i < 16; ++i) {
          unsigned lo = (unsigned)v0[i], hi = (unsigned)(v0[i] >> 32);
          if (((lo >> 16) ^ w0) | ((hi >> 16) ^ w0)) bad0 |= (1u << i);
        }
        if (u > 0) {
          #pragma unroll
          for (int i = 0; i < 16; ++i) {
            unsigned lo = (unsigned)v1[i], hi = (unsigned)(v1[i] >> 32);
            if (((lo >> 16) ^ w1) | ((hi >> 16) ^ w1)) bad1 |= (1u << i);
          }
        }
        if (!(bad0 | bad1)) break;
        if (++spins > 4000000u) break;
        #pragma unroll
        for (int i = 0; i < 16; ++i) {
          if (bad0 & (1u << i)) v0[i] = ld_u64(s0 + tid + i * 256);
          if (bad1 & (1u << i)) v1[i] = ld_u64(s1 + tid + i * 256);
        }
      }
      unsigned* db = sH + (u & 1) * 8320;
      #pragma unroll
      for (int i = 0; i < 16; ++i) {
        int j = tid + i * 256;
        db[(j >> 8) * 260 + (j & 255)] = payload(v0[i]);
      }
      if (u > 0) {
        #pragma unroll
        for (int i = 0; i < 16; ++i) {
          int j = tid + i * 256;
          db[4160 + (j >> 8) * 260 + (j & 255)] = payload(v1[i]);
        }
      }
      __syncthreads();                           // all verifies + stages done
      if (tid == 0) st_u32(prog + q, (unsigned)(u + 1));

      const char* cur = (const char*)db;
      f32x4 a0 = {0,0,0,0}, a1 = {0,0,0,0};
      #pragma unroll
      for (int f = 0; f < 16; ++f) {             // Wih1 * h0(u)
        f16x8 bf = *(const f16x8*)(cur + rowb + f * 64);
        if (f & 1) a1 = mfma16(wA[f], bf, a1); else a0 = mfma16(wA[f], bf, a0);
      }
      #pragma unroll
      for (int f = 0; f < 16; ++f) {             // Whh1 * h1(u-1)
        f16x8 bf = *(const f16x8*)(cur + 16640 + rowb + f * 64);
        if (f & 1) a1 = mfma16(wA[16 + f], bf, a1); else a0 = mfma16(wA[16 + f], bf, a0);
      }
      f32x4 a = a0 + a1;
      float ii = sigm(a[0] + bias0[0]);
      float ff = sigm(a[1] + bias0[1]);
      float gg = tanhx(a[2] + bias0[2]);
      float oo = sigm(a[3] + bias0[3]);
      c0 = ff * c0 + ii * gg;
      float hv = oo * tanhx(c0);

      unsigned tag = (unsigned)(u + 1) << 16;
      unsigned hu = (unsigned)__builtin_bit_cast(unsigned short, (_Float16)hv);
      unsigned* dst = gbase + H1_OFF + (u % D1) * H0_SLOT + bcol * 512 + hb + kgrp;
      st_u32(dst, hu | tag);
    }
  }

  // ---- FC epilogue: out = relu([h0_T; h1_T] @ fc_w^T + fc_b), [128][1024]
  const int fid = g * 48 + r;
  if (fid < 128) {
    const int rt = fid >> 4, ct = fid & 15;
    const int sg = rt & 3;
    const bool isH1 = (rt >= 4);
    // h0_T = h0(1023): slot 1023%5=3, tag 1024. h1_T = h1(1023): slot 0, tag 1024.
    const u64t* src = (const u64t*)(ws + sg * GRP_U32
                                    + (isH1 ? (H1_OFF + 0 * H0_SLOT) : (3 * H0_SLOT)));
    const unsigned want = (unsigned)T_SEQ;
    u64t v[16];
    #pragma unroll
    for (int i = 0; i < 16; ++i) v[i] = ld_u64(src + tid + i * 256);
    for (;;) {
      unsigned bad = 0;
      #pragma unroll
      for (int i = 0; i < 16; ++i) {
        unsigned lo = (unsigned)v[i], hi = (unsigned)(v[i] >> 32);
        if (((lo >> 16) ^ want) | ((hi >> 16) ^ want)) bad |= (1u << i);
      }
      if (!bad) break;
      if (++spins > 4000000u) break;
      __builtin_amdgcn_s_sleep(1);
      #pragma unroll
      for (int i = 0; i < 16; ++i)
        if (bad & (1u << i)) v[i] = ld_u64(src + tid + i * 256);
    }
    __syncthreads();
    #pragma unroll
    for (int i = 0; i < 16; ++i) {
      int j = tid + i * 256;
      sH[(j >> 8) * 260 + (j & 255)] = payload(v[i]);
    }
    __syncthreads();
    const int col = ct * 64 + wv * 16 + bcol;
    f32x4 a0 = {0,0,0,0}, a1 = {0,0,0,0};
    #pragma unroll
    for (int f = 0; f < 16; ++f) {               // K = 512
      f16x8 af = *(const f16x8*)((const char*)sH + rowb + f * 64);
      f16x8 bf = cvt8(fcw + (size_t)col * H + f * 32 + kgrp * 8);
      if (f & 1) a1 = mfma16(af, bf, a1); else a0 = mfma16(af, bf, a0);
    }
    f32x4 a = a0 + a1;
    const float fb = fcb[col];
    #pragma unroll
    for (int rr = 0; rr < 4; ++rr) {
      int row = rt * 16 + kgrp * 4 + rr;
      float v2 = a[rr] + fb;
      out[(size_t)row * 1024 + col] = v2 > 0.f ? v2 : 0.f;
    }
  }
}

extern "C" void kernel_launch(void* const* d_in, const int* in_sizes, int n_in,
                              void* d_out, int out_size, void* d_ws, size_t ws_size,
                              hipStream_t stream) {
  const float* x    = (const float*)d_in[0];
  const float* Wih0 = (const float*)d_in[1];
  const float* Whh0 = (const float*)d_in[2];
  const float* bih0 = (const float*)d_in[3];
  const float* bhh0 = (const float*)d_in[4];
  const float* Wih1 = (const float*)d_in[5];
  const float* Whh1 = (const float*)d_in[6];
  const float* bih1 = (const float*)d_in[7];
  const float* bhh1 = (const float*)d_in[8];
  const float* fcw  = (const float*)d_in[9];
  const float* fcb  = (const float*)d_in[10];
  (void)in_sizes; (void)n_in; (void)out_size; (void)ws_size;

  // zero rings + progress every call (tag 0 never matches wanted tags >= 1)
  hipMemsetAsync(d_ws, 0, WS_BYTES, stream);
  lstm_fused<<<dim3(48, 4), dim3(256), 0, stream>>>(
      x, Wih0, Whh0, bih0, bhh0, Wih1, Whh1, bih1, bhh1, fcw, fcb,
      (float*)d_out, (unsigned*)d_ws);
}